// Round 7
// baseline (863.103 us; speedup 1.0000x reference)
//
#include <hip/hip_runtime.h>
#include <hip/hip_bf16.h>
#include <math.h>

#define Bz 4
#define Dch 512
#define Tseq 1024
#define Lnum 6
#define Hn 8
#define DF 2048
#define NTOK (Bz * Tseq)   // 4096

typedef __attribute__((ext_vector_type(8))) short bf16x8;
typedef __attribute__((ext_vector_type(4))) float f32x4;

__device__ __forceinline__ ushort f2bf(float x) {
    __hip_bfloat16 h = __float2bfloat16(x);
    return *(ushort*)&h;
}

// ---------------------------------------------------------------------------
// Transpose in: x[b,d,t] -> X[(b*T+t), d] * mask  (f32 + bf16 copies)
// ---------------------------------------------------------------------------
__global__ __launch_bounds__(256) void tin_kernel(const float* __restrict__ x,
                                                  const float* __restrict__ m,
                                                  float* __restrict__ X,
                                                  ushort* __restrict__ Xbf) {
    __shared__ float tile[32][33];
    int t0 = blockIdx.x * 32, d0 = blockIdx.y * 32, b = blockIdx.z;
    int tx = threadIdx.x % 32, ty = threadIdx.x / 32;  // 32 x 8
    #pragma unroll
    for (int i = 0; i < 32; i += 8)
        tile[ty + i][tx] = x[((size_t)b * Dch + d0 + ty + i) * Tseq + t0 + tx];
    __syncthreads();
    #pragma unroll
    for (int i = 0; i < 32; i += 8) {
        int trow = ty + i;
        float mk = m[(size_t)b * Tseq + t0 + trow];
        float val = tile[tx][trow] * mk;
        size_t o = ((size_t)b * Tseq + t0 + trow) * Dch + d0 + tx;
        X[o] = val;
        Xbf[o] = f2bf(val);
    }
}

// ---------------------------------------------------------------------------
// Transpose out: X[(b*T+t), d] * mask -> out[b,d,t]
// ---------------------------------------------------------------------------
__global__ __launch_bounds__(256) void tout_kernel(const float* __restrict__ X,
                                                   const float* __restrict__ m,
                                                   float* __restrict__ out) {
    __shared__ float tile[32][33];
    int t0 = blockIdx.x * 32, d0 = blockIdx.y * 32, b = blockIdx.z;
    int tx = threadIdx.x % 32, ty = threadIdx.x / 32;
    #pragma unroll
    for (int i = 0; i < 32; i += 8)
        tile[ty + i][tx] = X[((size_t)b * Tseq + t0 + ty + i) * Dch + d0 + tx];
    __syncthreads();
    #pragma unroll
    for (int i = 0; i < 32; i += 8) {
        int drow = d0 + ty + i;
        float mk = m[(size_t)b * Tseq + t0 + tx];
        out[((size_t)b * Dch + drow) * Tseq + t0 + tx] = tile[tx][ty + i] * mk;
    }
}

// ---------------------------------------------------------------------------
// Per-layer weight f32 -> bf16 conversion into one packed scratch.
// ---------------------------------------------------------------------------
__global__ __launch_bounds__(256) void wconv_kernel(const float* __restrict__ wq,
                                                    const float* __restrict__ wk,
                                                    const float* __restrict__ wv,
                                                    const float* __restrict__ wo,
                                                    const float* __restrict__ w1,
                                                    const float* __restrict__ w2,
                                                    ushort* __restrict__ dst) {
    for (size_t q = (size_t)blockIdx.x * blockDim.x + threadIdx.x; q < 786432;
         q += (size_t)gridDim.x * blockDim.x) {
        size_t e = q * 4;
        const float* src;
        size_t off;
        if (e < 1048576) {
            int r = (int)(e >> 18);
            src = r == 0 ? wq : r == 1 ? wk : r == 2 ? wv : wo;
            off = e & 262143;
        } else if (e < 2097152) {
            src = w1; off = e - 1048576;
        } else {
            src = w2; off = e - 2097152;
        }
        float4 v = *(const float4*)&src[off];
        ushort4 o;
        o.x = f2bf(v.x); o.y = f2bf(v.y); o.z = f2bf(v.z); o.w = f2bf(v.w);
        *(ushort4*)&dst[e] = o;
    }
}

// ---------------------------------------------------------------------------
// bf16 MFMA GEMM: C[M,N] = act(A[M,K] * W[N,K]^T + bias).
// BM=128, BN=64, BK=64; 256 thr = 4 waves, wave w owns rows w*32..w*32+31,
// all 64 cols: 2x4 16x16 frags, 16 MFMA : 12 ds_read_b128 per K-step.
// LDS 24 KB, chunk-XOR swizzle (both-sides rule).
// NSEL=3: blockIdx.y*64 picks (W,bias,C) from 3 regions of 512 cols (QKV).
// SPLITK=1: blockIdx.z halves K; z=1 writes Cb without bias.
// ---------------------------------------------------------------------------
template <int ACT, int OBF, int NSEL, int SPLITK>
__global__ __launch_bounds__(256) void gemm_bf(const ushort* __restrict__ A, int lda,
                                               const ushort* __restrict__ Wa,
                                               const ushort* __restrict__ Wb,
                                               const ushort* __restrict__ Wc,
                                               const float* __restrict__ ba,
                                               const float* __restrict__ bb,
                                               const float* __restrict__ bc,
                                               void* __restrict__ Ca,
                                               void* __restrict__ Cb,
                                               void* __restrict__ Cc,
                                               int ldc, int Kdim) {
    __shared__ ushort As[128 * 64];
    __shared__ ushort Bs[64 * 64];
    const int bm = blockIdx.x * 128;
    int sel = 0, cb = blockIdx.y * 64;
    if (NSEL == 3) { sel = cb >> 9; cb &= 511; }
    const ushort* W = sel == 0 ? Wa : sel == 1 ? Wb : Wc;
    const float* bias = sel == 0 ? ba : sel == 1 ? bb : bc;
    void* C = sel == 0 ? Ca : sel == 1 ? Cb : Cc;

    int Klen = Kdim, kb = 0;
    bool zhalf = false;
    if (SPLITK) {
        Klen = Kdim >> 1;
        zhalf = (blockIdx.z != 0);
        kb = zhalf ? Klen : 0;
        if (zhalf) C = Cb;
    }

    const int tid = threadIdx.x;
    const int wid = tid >> 6, lane = tid & 63;
    const int lq = lane & 15, lk = lane >> 4;

    f32x4 acc[2][4];
    #pragma unroll
    for (int i = 0; i < 2; ++i)
        #pragma unroll
        for (int j = 0; j < 4; ++j) acc[i][j] = (f32x4){0.f, 0.f, 0.f, 0.f};

    for (int k0 = 0; k0 < Klen; k0 += 64) {
        #pragma unroll
        for (int s = 0; s < 4; ++s) {
            int cid = s * 256 + tid;
            int row = cid >> 3, cp = cid & 7;
            int lc = cp ^ (row & 7);          // pre-swizzled source chunk
            const ushort* sa = A + (size_t)(bm + row) * lda + kb + k0 + lc * 8;
            __builtin_amdgcn_global_load_lds(
                (const __attribute__((address_space(1))) void*)sa,
                (__attribute__((address_space(3))) void*)&As[cid * 8], 16, 0, 0);
            if (s < 2) {
                const ushort* sb = W + (size_t)(cb + row) * Kdim + kb + k0 + lc * 8;
                __builtin_amdgcn_global_load_lds(
                    (const __attribute__((address_space(1))) void*)sb,
                    (__attribute__((address_space(3))) void*)&Bs[cid * 8], 16, 0, 0);
            }
        }
        __syncthreads();

        bf16x8 af[2][2], bg[4][2];
        #pragma unroll
        for (int mf = 0; mf < 2; ++mf)
            #pragma unroll
            for (int kf = 0; kf < 2; ++kf) {
                int row = wid * 32 + mf * 16 + lq;
                af[mf][kf] = *(const bf16x8*)&As[row * 64 + (((kf * 4 + lk) ^ (row & 7)) * 8)];
            }
        #pragma unroll
        for (int nf = 0; nf < 4; ++nf)
            #pragma unroll
            for (int kf = 0; kf < 2; ++kf) {
                int row = nf * 16 + lq;
                bg[nf][kf] = *(const bf16x8*)&Bs[row * 64 + (((kf * 4 + lk) ^ (row & 7)) * 8)];
            }
        #pragma unroll
        for (int mf = 0; mf < 2; ++mf)
            #pragma unroll
            for (int nf = 0; nf < 4; ++nf)
                #pragma unroll
                for (int kf = 0; kf < 2; ++kf)
                    acc[mf][nf] = __builtin_amdgcn_mfma_f32_16x16x32_bf16(
                        af[mf][kf], bg[nf][kf], acc[mf][nf], 0, 0, 0);
        __syncthreads();
    }

    #pragma unroll
    for (int mf = 0; mf < 2; ++mf)
        #pragma unroll
        for (int r = 0; r < 4; ++r) {
            size_t row = bm + wid * 32 + mf * 16 + lk * 4 + r;
            #pragma unroll
            for (int nf = 0; nf < 4; ++nf) {
                int col = cb + nf * 16 + lq;
                float bv = (SPLITK && zhalf) ? 0.f : bias[col];
                float v = acc[mf][nf][r] + bv;
                if (ACT == 1) v = 0.5f * v * (1.f + erff(v * 0.70710678118654752f));
                if (OBF) ((ushort*)C)[row * ldc + col] = f2bf(v);
                else     ((float*)C)[row * ldc + col] = v;
            }
        }
}

// ---------------------------------------------------------------------------
// Flash attention, bf16 MFMA, KV-split over blockIdx.z (2 halves of 512 keys).
// Grid (16, 32, 2), 256 thr = 4 waves; each wave owns 16 q rows.
// Writes unnormalized U (f32) + per-row (m,l); recomb_kernel merges halves.
// Register-prefetch of next K/V tile; setprio around MFMA clusters.
// ---------------------------------------------------------------------------
__global__ __launch_bounds__(256) void fattn_kernel(const ushort* __restrict__ Q,
                                                    const ushort* __restrict__ K,
                                                    const ushort* __restrict__ V,
                                                    float* __restrict__ Up,
                                                    float2* __restrict__ ML) {
    int qt = blockIdx.x;
    int bh = blockIdx.y;
    int s = blockIdx.z;
    int b = bh >> 3, h = bh & 7;
    int q0 = qt * 64;
    int tid = threadIdx.x;
    int wid = tid >> 6, lane = tid & 63;
    int lq = lane & 15, lk = lane >> 4;

    __shared__ short Qs[64][72];
    __shared__ short Ks[64][72];
    __shared__ short Vt[64][72];       // [d][key ^ ((d>>3)<<3)]
    __shared__ short Ps[4][16][72];    // per-wave P strip

    const size_t base = ((size_t)b * Tseq) * Dch + (size_t)h * 64;
    const int kvbase = s * 512;

    // stage Q tile
    #pragma unroll
    for (int i = 0; i < 2; ++i) {
        int e = tid + i * 256;
        int row = e >> 3, c8 = e & 7;
        *(bf16x8*)&Qs[row][c8 * 8] =
            *(const bf16x8*)&Q[base + (size_t)(q0 + row) * Dch + c8 * 8];
    }

    // prefetch k-tile 0 into regs
    bf16x8 kreg[2], vreg[2];
    #pragma unroll
    for (int i = 0; i < 2; ++i) {
        int e = tid + i * 256;
        int row = e >> 3, c8 = e & 7;
        kreg[i] = *(const bf16x8*)&K[base + (size_t)(kvbase + row) * Dch + c8 * 8];
        vreg[i] = *(const bf16x8*)&V[base + (size_t)(kvbase + row) * Dch + c8 * 8];
    }

    __syncthreads();
    bf16x8 qa0 = *(const bf16x8*)&Qs[wid * 16 + lq][lk * 8];
    bf16x8 qa1 = *(const bf16x8*)&Qs[wid * 16 + lq][lk * 8 + 32];

    float mrun[4], lrun[4];
    f32x4 Oacc[4];
    #pragma unroll
    for (int r = 0; r < 4; ++r) { mrun[r] = -1e30f; lrun[r] = 0.f; }
    #pragma unroll
    for (int d = 0; d < 4; ++d) Oacc[d] = (f32x4){0.f, 0.f, 0.f, 0.f};

    for (int kt = 0; kt < 8; ++kt) {
        if (kt > 0) __syncthreads();   // prior tile's LDS reads (incl. PV) done
        // write prefetched regs to LDS
        #pragma unroll
        for (int i = 0; i < 2; ++i) {
            int e = tid + i * 256;
            int row = e >> 3, c8 = e & 7;
            *(bf16x8*)&Ks[row][c8 * 8] = kreg[i];
            int kcol = row ^ (c8 << 3);
            #pragma unroll
            for (int j = 0; j < 8; ++j) Vt[c8 * 8 + j][kcol] = vreg[i][j];
        }
        __syncthreads();

        // issue next tile's loads (latency hides under compute below)
        if (kt < 7) {
            int k0n = kvbase + (kt + 1) * 64;
            #pragma unroll
            for (int i = 0; i < 2; ++i) {
                int e = tid + i * 256;
                int row = e >> 3, c8 = e & 7;
                kreg[i] = *(const bf16x8*)&K[base + (size_t)(k0n + row) * Dch + c8 * 8];
                vreg[i] = *(const bf16x8*)&V[base + (size_t)(k0n + row) * Dch + c8 * 8];
            }
        }

        // QK^T
        f32x4 sc[4];
        __builtin_amdgcn_s_setprio(1);
        #pragma unroll
        for (int nt = 0; nt < 4; ++nt) {
            f32x4 a = (f32x4){0.f, 0.f, 0.f, 0.f};
            bf16x8 kb0 = *(const bf16x8*)&Ks[nt * 16 + lq][lk * 8];
            bf16x8 kb1 = *(const bf16x8*)&Ks[nt * 16 + lq][lk * 8 + 32];
            a = __builtin_amdgcn_mfma_f32_16x16x32_bf16(qa0, kb0, a, 0, 0, 0);
            a = __builtin_amdgcn_mfma_f32_16x16x32_bf16(qa1, kb1, a, 0, 0, 0);
            sc[nt] = a;
        }
        __builtin_amdgcn_s_setprio(0);

        // online softmax (rows lk*4+r, cols over 16 lanes x 4 nt)
        float alpha[4];
        #pragma unroll
        for (int r = 0; r < 4; ++r) {
            #pragma unroll
            for (int nt = 0; nt < 4; ++nt) sc[nt][r] *= 0.125f;
            float t = fmaxf(fmaxf(sc[0][r], sc[1][r]), fmaxf(sc[2][r], sc[3][r]));
            #pragma unroll
            for (int off = 1; off < 16; off <<= 1) t = fmaxf(t, __shfl_xor(t, off));
            float mnew = fmaxf(mrun[r], t);
            alpha[r] = __expf(mrun[r] - mnew);
            mrun[r] = mnew;
            float acc = 0.f;
            #pragma unroll
            for (int nt = 0; nt < 4; ++nt) {
                float p = __expf(sc[nt][r] - mnew);
                sc[nt][r] = p;
                acc += p;
            }
            #pragma unroll
            for (int off = 1; off < 16; off <<= 1) acc += __shfl_xor(acc, off);
            lrun[r] = lrun[r] * alpha[r] + acc;
        }

        #pragma unroll
        for (int nt = 0; nt < 4; ++nt)
            #pragma unroll
            for (int r = 0; r < 4; ++r)
                Ps[wid][lk * 4 + r][nt * 16 + lq] = (short)f2bf(sc[nt][r]);

        // guarantee P-store -> ds_read_b128 ordering (proven fix)
        __syncthreads();

        #pragma unroll
        for (int d = 0; d < 4; ++d)
            #pragma unroll
            for (int r = 0; r < 4; ++r) Oacc[d][r] *= alpha[r];

        __builtin_amdgcn_s_setprio(1);
        #pragma unroll
        for (int dt = 0; dt < 4; ++dt) {
            int drow = dt * 16 + lq;
            int sw = (drow >> 3) << 3;
            bf16x8 pa0 = *(const bf16x8*)&Ps[wid][lq][lk * 8];
            bf16x8 pa1 = *(const bf16x8*)&Ps[wid][lq][lk * 8 + 32];
            bf16x8 vb0 = *(const bf16x8*)&Vt[drow][(lk * 8) ^ sw];
            bf16x8 vb1 = *(const bf16x8*)&Vt[drow][(lk * 8 + 32) ^ sw];
            Oacc[dt] = __builtin_amdgcn_mfma_f32_16x16x32_bf16(pa0, vb0, Oacc[dt], 0, 0, 0);
            Oacc[dt] = __builtin_amdgcn_mfma_f32_16x16x32_bf16(pa1, vb1, Oacc[dt], 0, 0, 0);
        }
        __builtin_amdgcn_s_setprio(0);
    }

    // epilogue: store unnormalized U (f32) + (m,l) per row
    #pragma unroll
    for (int r = 0; r < 4; ++r) {
        int rowq = q0 + wid * 16 + lk * 4 + r;
        if (lq == 0)
            ML[(size_t)(s * 32 + bh) * Tseq + rowq] = make_float2(mrun[r], lrun[r]);
        size_t o = (size_t)s * NTOK * Dch + ((size_t)b * Tseq + rowq) * Dch + h * 64;
        #pragma unroll
        for (int dt = 0; dt < 4; ++dt)
            Up[o + dt * 16 + lq] = Oacc[dt][r];
    }
}

// ---------------------------------------------------------------------------
// Recombine the two KV-halves: O = (U0*w0 + U1*w1) / (l0*w0 + l1*w1), bf16.
// ---------------------------------------------------------------------------
__global__ __launch_bounds__(256) void recomb_kernel(const float* __restrict__ Up,
                                                     const float2* __restrict__ ML,
                                                     ushort* __restrict__ O) {
    int t = blockIdx.x * 256 + threadIdx.x;
    size_t e = (size_t)t * 4;
    int row = (int)(e >> 9);
    int col = (int)(e & 511);
    int bh = ((row >> 10) << 3) | (col >> 6);
    int q = row & 1023;
    float2 a = ML[(size_t)bh * Tseq + q];
    float2 c = ML[(size_t)(32 + bh) * Tseq + q];
    float m = fmaxf(a.x, c.x);
    float w0 = __expf(a.x - m), w1 = __expf(c.x - m);
    float inv = 1.f / (a.y * w0 + c.y * w1);
    float4 u0 = *(const float4*)&Up[e];
    float4 u1 = *(const float4*)&Up[(size_t)NTOK * Dch + e];
    ushort4 o;
    o.x = f2bf((u0.x * w0 + u1.x * w1) * inv);
    o.y = f2bf((u0.y * w0 + u1.y * w1) * inv);
    o.z = f2bf((u0.z * w0 + u1.z * w1) * inv);
    o.w = f2bf((u0.w * w0 + u1.w * w1) * inv);
    *(ushort4*)&O[e] = o;
}

// ---------------------------------------------------------------------------
// Residual add + LayerNorm over channels; optional 2nd partial Y2 (split-K).
// ---------------------------------------------------------------------------
__global__ __launch_bounds__(256) void add_ln_kernel(const float* X, const float* Y,
                                                     const float* Y2,
                                                     const float* __restrict__ g,
                                                     const float* __restrict__ bta,
                                                     float* Xout, ushort* Xbf) {
    int token = blockIdx.x * 4 + threadIdx.x / 64;
    int lane = threadIdx.x % 64;
    const float* xr = &X[(size_t)token * Dch];
    const float* yr = &Y[(size_t)token * Dch];
    const float* y2r = Y2 ? &Y2[(size_t)token * Dch] : nullptr;
    float v[8];
    float sum = 0.f;
    #pragma unroll
    for (int i = 0; i < 8; ++i) {
        v[i] = xr[lane + i * 64] + yr[lane + i * 64];
        if (Y2) v[i] += y2r[lane + i * 64];
        sum += v[i];
    }
    #pragma unroll
    for (int off = 32; off; off >>= 1) sum += __shfl_xor(sum, off);
    float mu = sum * (1.f / Dch);
    float var = 0.f;
    #pragma unroll
    for (int i = 0; i < 8; ++i) {
        float d = v[i] - mu;
        var += d * d;
    }
    #pragma unroll
    for (int off = 32; off; off >>= 1) var += __shfl_xor(var, off);
    float rstd = rsqrtf(var * (1.f / Dch) + 1e-5f);
    #pragma unroll
    for (int i = 0; i < 8; ++i) {
        int c = lane + i * 64;
        float o = (v[i] - mu) * rstd * g[c] + bta[c];
        Xout[(size_t)token * Dch + c] = o;
        Xbf[(size_t)token * Dch + c] = f2bf(o);
    }
}

// ---------------------------------------------------------------------------
// Workspace map (floats from ws base) — total 15204352 floats = 60.8 MB,
// identical footprint to the round-4 layout that passed on hardware.
//   X    @        0  (2097152)                      f32 [4096,512]
//   Yb   @  2097152  (2097152)  -- ML overlays its tail @ 4063232 (131072)
//   Xbf  @  4194304  (1048576)                      bf16 [4096,512]
//   Qbf  @  5242880  (1048576)  \__ Y2 (f32 [4096,512]) overlays Qbf+Kbf
//   Kbf  @  6291456  (1048576)  /   (dead after fattn; Y2 lives F2->add_ln2)
//   Vbf  @  7340032  (1048576)
//   Obf  @  8388608  (1048576)
//   Hbf  @  9437184  (4194304)  -- Up (f32 2x[4096,512]) overlays (disjoint)
//   Wbf  @ 13631488  (1572864)                      bf16 per-layer weights
// ---------------------------------------------------------------------------
extern "C" void kernel_launch(void* const* d_in, const int* in_sizes, int n_in,
                              void* d_out, int out_size, void* d_ws, size_t ws_size,
                              hipStream_t stream) {
    const float* x  = (const float*)d_in[0];
    const float* xm = (const float*)d_in[1];
    const float* Wq = (const float*)d_in[2];
    const float* bq = (const float*)d_in[3];
    const float* Wk = (const float*)d_in[4];
    const float* bk = (const float*)d_in[5];
    const float* Wv = (const float*)d_in[6];
    const float* bv = (const float*)d_in[7];
    const float* Wo = (const float*)d_in[8];
    const float* bo = (const float*)d_in[9];
    const float* W1 = (const float*)d_in[10];
    const float* b1 = (const float*)d_in[11];
    const float* W2 = (const float*)d_in[12];
    const float* b2 = (const float*)d_in[13];
    const float* g1 = (const float*)d_in[14];
    const float* be1 = (const float*)d_in[15];
    const float* g2 = (const float*)d_in[16];
    const float* be2 = (const float*)d_in[17];

    float* ws = (float*)d_ws;
    float*  X   = ws;
    float*  Yb  = ws + 2097152;
    float2* ML  = (float2*)(ws + 4063232);              // tail of Yb (dead at fattn)
    ushort* Xbf = (ushort*)(ws + 4194304);
    ushort* Qbf = (ushort*)(ws + 5242880);
    float*  Y2  = ws + 5242880;                         // overlays Qbf+Kbf
    ushort* Kbf = (ushort*)(ws + 6291456);
    ushort* Vbf = (ushort*)(ws + 7340032);
    ushort* Obf = (ushort*)(ws + 8388608);
    ushort* Hbf = (ushort*)(ws + 9437184);
    float*  Up  = ws + 9437184;                         // overlays Hbf
    ushort* Wbf = (ushort*)(ws + 13631488);

    ushort* wq = Wbf;
    ushort* wk = Wbf + 262144;
    ushort* wv = Wbf + 524288;
    ushort* wo = Wbf + 786432;
    ushort* w1 = Wbf + 1048576;
    ushort* w2 = Wbf + 2097152;

    tin_kernel<<<dim3(Tseq / 32, Dch / 32, Bz), 256, 0, stream>>>(x, xm, X, Xbf);

    for (int l = 0; l < Lnum; ++l) {
        wconv_kernel<<<1536, 256, 0, stream>>>(
            Wq + (size_t)l * 262144, Wk + (size_t)l * 262144, Wv + (size_t)l * 262144,
            Wo + (size_t)l * 262144, W1 + (size_t)l * 1048576, W2 + (size_t)l * 1048576,
            Wbf);

        gemm_bf<0, 1, 3, 0><<<dim3(32, 24), 256, 0, stream>>>(
            Xbf, Dch, wq, wk, wv, bq + l * Dch, bk + l * Dch, bv + l * Dch,
            Qbf, Kbf, Vbf, Dch, Dch);

        fattn_kernel<<<dim3(16, 32, 2), 256, 0, stream>>>(Qbf, Kbf, Vbf, Up, ML);
        recomb_kernel<<<2048, 256, 0, stream>>>(Up, ML, Obf);

        gemm_bf<0, 0, 1, 0><<<dim3(32, 8), 256, 0, stream>>>(
            Obf, Dch, wo, wo, wo, bo + l * Dch, bo + l * Dch, bo + l * Dch,
            Yb, Yb, Yb, Dch, Dch);

        add_ln_kernel<<<NTOK / 4, 256, 0, stream>>>(X, Yb, nullptr,
                                                    g1 + l * Dch, be1 + l * Dch, X, Xbf);

        gemm_bf<1, 1, 1, 0><<<dim3(32, 32), 256, 0, stream>>>(
            Xbf, Dch, w1, w1, w1, b1 + l * DF, b1 + l * DF, b1 + l * DF,
            Hbf, Hbf, Hbf, DF, Dch);

        gemm_bf<0, 0, 1, 1><<<dim3(32, 8, 2), 256, 0, stream>>>(
            Hbf, DF, w2, w2, w2,
            b2 + l * Dch, b2 + l * Dch, b2 + l * Dch,
            Yb, Y2, Yb, Dch, DF);

        add_ln_kernel<<<NTOK / 4, 256, 0, stream>>>(X, Yb, Y2,
                                                    g2 + l * Dch, be2 + l * Dch, X, Xbf);
    }

    tout_kernel<<<dim3(Tseq / 32, Dch / 32, Bz), 256, 0, stream>>>(X, xm, (float*)d_out);
}